// Round 7
// baseline (183.144 us; speedup 1.0000x reference)
//
#include <hip/hip_runtime.h>
#include <hip/hip_bf16.h>

// ---------- types ----------
typedef __attribute__((ext_vector_type(8))) short short8;      // 8 x bf16 (4 VGPR) MFMA frag
typedef __attribute__((ext_vector_type(4))) float f32x4;       // MFMA accumulator
typedef __attribute__((ext_vector_type(4))) unsigned short u16x4;

// ---------- constants ----------
// B=4, N=1024, C=768, H=12, Dh=64, 3C=2304, scale=(C*H)^-0.5 = 1/96 (96^2 = 9216 = C*H)
#define NB 4
#define NN 1024
#define NC 768
#define NH 12
#define TC 2304

// workspace byte offsets (kp reuses xb region: xb dead after gemm_qkv)
#define OFF_XB   0ul                       // x bf16 -> later kp   6291456
#define OFF_WQ   6291456ul                 // qkv_w bf16      2304*768*2  = 3538944
#define OFF_WMU  (OFF_WQ + 3538944ul)      // mu_w bf16       768*384*2   = 589824
#define OFF_WLS  (OFF_WMU + 589824ul)      // ls_w bf16
#define OFF_QKVB (OFF_WLS + 589824ul)      // qkv bf16        4096*2304*2 = 18874368
#define OFF_V3   (OFF_QKVB + 18874368ul)   // v frag-packed   48*1024*64*2= 6291456
#define OFF_OUTB (OFF_V3 + 6291456ul)      // attn-out bf16   4096*768*2  = 6291456

__device__ __forceinline__ unsigned short f2bf(float f) {
    unsigned int u = __float_as_uint(f);
    u = (u + 0x7FFFu + ((u >> 16) & 1u)) >> 16;
    return (unsigned short)u;
}

__device__ __forceinline__ void gload_lds16(const unsigned short* g, unsigned short* l) {
    __builtin_amdgcn_global_load_lds(
        (const __attribute__((address_space(1))) unsigned int*)g,
        (__attribute__((address_space(3))) unsigned int*)l, 16, 0, 0);
}

// inline-asm loads: volatile -> fixed issue order in the vmcnt FIFO
__device__ __forceinline__ void gload16(short8& dst, const unsigned short* p) {
    asm volatile("global_load_dwordx4 %0, %1, off" : "=v"(dst) : "v"(p));
}
__device__ __forceinline__ void gloadf4(f32x4& dst, const float* p) {
    asm volatile("global_load_dwordx4 %0, %1, off" : "=v"(dst) : "v"(p));
}
#define WAITV(N) do { asm volatile("s_waitcnt vmcnt(" #N ")" ::: "memory"); \
                      __builtin_amdgcn_sched_barrier(0); } while (0)
#define SBAR()   __builtin_amdgcn_sched_barrier(0)

// ---------- fused cast f32 -> bf16 ----------
__global__ void cast_all(const float* __restrict__ x, const float* __restrict__ qkv_w,
                         const float* __restrict__ mu_w, const float* __restrict__ ls_w,
                         unsigned short* __restrict__ dst) {
    int i = blockIdx.x * blockDim.x + threadIdx.x;   // float4 index
    const float* src; int off;
    if (i < 786432)            { src = x;     off = i; }
    else if (i < 1228800)      { src = qkv_w; off = i - 786432; }
    else if (i < 1302528)      { src = mu_w;  off = i - 1228800; }
    else                       { src = ls_w;  off = i - 1302528; }
    f32x4 v = ((const f32x4*)src)[off];
    u16x4 o;
#pragma unroll
    for (int j = 0; j < 4; ++j) o[j] = f2bf(v[j]);
    ((u16x4*)dst)[i] = o;
}

// ---------- shared GEMM body (unchanged, validated) ----------
template <int EPI>
__device__ __forceinline__ void gemm_body(
    unsigned short* As, unsigned short* Bs,
    const unsigned short* __restrict__ A, const unsigned short* __restrict__ Bm,
    int K, int lda, int ldb, void* __restrict__ Cout, int ldc,
    const float* __restrict__ bias, int row0, int col0)
{
    const int t = threadIdx.x;
    const int lane = t & 63;
    const int wv = t >> 6;
    const int wm = wv >> 1, wn = wv & 1;
    const int li = lane & 15;
    const int koff = (lane >> 4) * 8;

    f32x4 acc[4][4] = {};

    const int tr = t >> 2;
    const int tc = (t & 3) * 8;
    const unsigned short* ag = A + (size_t)(row0 + tr) * lda + tc;
    const unsigned short* bg = Bm + (size_t)(col0 + tr) * ldb + tc;

    for (int kt = 0; kt < K; kt += 32) {
        gload_lds16(ag,            As + t * 8);
        gload_lds16(ag + 64 * lda, As + 2048 + t * 8);
        gload_lds16(bg,            Bs + t * 8);
        gload_lds16(bg + 64 * ldb, Bs + 2048 + t * 8);
        ag += 32; bg += 32;
        __syncthreads();
        short8 af[4], bf[4];
#pragma unroll
        for (int m = 0; m < 4; ++m)
            af[m] = *(const short8*)&As[(wm * 64 + m * 16 + li) * 32 + koff];
#pragma unroll
        for (int n = 0; n < 4; ++n)
            bf[n] = *(const short8*)&Bs[(wn * 64 + n * 16 + li) * 32 + koff];
#pragma unroll
        for (int m = 0; m < 4; ++m)
#pragma unroll
            for (int n = 0; n < 4; ++n)
                acc[m][n] = __builtin_amdgcn_mfma_f32_16x16x32_bf16(af[m], bf[n], acc[m][n], 0, 0, 0);
        __syncthreads();
    }

#pragma unroll
    for (int m = 0; m < 4; ++m) {
        const int row = row0 + wm * 64 + m * 16 + (lane >> 4) * 4;
#pragma unroll
        for (int n = 0; n < 4; ++n) {
            const int col = col0 + wn * 64 + n * 16 + li;
#pragma unroll
            for (int r = 0; r < 4; ++r) {
                if (EPI == 0) {
                    ((unsigned short*)Cout)[(size_t)(row + r) * ldc + col] = f2bf(acc[m][n][r]);
                } else {
                    ((float*)Cout)[(size_t)(row + r) * ldc + col] = acc[m][n][r] + bias[col];
                }
            }
        }
    }
}

__global__ __launch_bounds__(256, 2) void gemm_qkv(
    const unsigned short* __restrict__ A, const unsigned short* __restrict__ Bm,
    unsigned short* __restrict__ C)
{
    __shared__ unsigned short As[128 * 32];
    __shared__ unsigned short Bs[128 * 32];
    const int bid = blockIdx.y * gridDim.x + blockIdx.x;
    const int nwg = gridDim.x * gridDim.y;
    const int swz = (bid & 7) * (nwg >> 3) + (bid >> 3);
    const int row0 = (swz / gridDim.x) * 128;
    const int col0 = (swz % gridDim.x) * 128;
    gemm_body<0>(As, Bs, A, Bm, NC, NC, NC, C, TC, nullptr, row0, col0);
}

__global__ __launch_bounds__(256, 2) void gemm_heads(
    const unsigned short* __restrict__ outb,
    const unsigned short* __restrict__ wmu, const unsigned short* __restrict__ wls,
    const float* __restrict__ mu_b, const float* __restrict__ ls_b,
    float* __restrict__ out_mu, float* __restrict__ out_ls)
{
    __shared__ unsigned short As[128 * 32];
    __shared__ unsigned short Bs[128 * 32];
    const int bid = blockIdx.y * gridDim.x + blockIdx.x;
    const int nwg = gridDim.x * gridDim.y;
    const int swz = (bid & 7) * (nwg >> 3) + (bid >> 3);
    const int row0 = (swz / gridDim.x) * 128;
    const int col0 = (swz % gridDim.x) * 128;
    const int z = blockIdx.z;
    gemm_body<1>(As, Bs, outb + (z ? 384 : 0), z ? wls : wmu, 384, NC, 384,
                 z ? (void*)out_ls : (void*)out_mu, NC, z ? ls_b : mu_b, row0, col0);
}

// ---------- pack K (swizzled per-head rows) + V (frag-order) ----------
__global__ __launch_bounds__(256, 4) void pack_kv(
    const unsigned short* __restrict__ qkvb, unsigned short* __restrict__ kp,
    unsigned short* __restrict__ v3)
{
    __shared__ unsigned short tile[64][65];
    const int t = threadIdx.x;
    const int bh = blockIdx.y;
    const int b = bh / NH, h = bh % NH;
    const int m0 = blockIdx.x * 64;
#pragma unroll
    for (int i = 0; i < 2; ++i) {
        int lin = i * 256 + t;
        int mr = lin >> 3;                 // 0..63
        int dr = (lin & 7) * 8;            // shorts
        short8 v = *(const short8*)(qkvb + (size_t)(b * NN + m0 + mr) * TC + 768 + h * 64 + dr);
        int dbyte = (dr * 2) ^ ((mr & 7) << 4);
        *(short8*)(kp + (size_t)(bh * NN + m0 + mr) * 64 + (dbyte >> 1)) = v;
    }
#pragma unroll
    for (int i = 0; i < 2; ++i) {
        int lin = i * 256 + t;
        int mr = lin >> 3;
        int dr = (lin & 7) * 8;
        short8 v = *(const short8*)(qkvb + (size_t)(b * NN + m0 + mr) * TC + 1536 + h * 64 + dr);
#pragma unroll
        for (int j = 0; j < 8; ++j) tile[mr][dr + j] = (unsigned short)v[j];
    }
    __syncthreads();
#pragma unroll
    for (int i = 0; i < 2; ++i) {
        int lin = i * 256 + t;
        int dw = lin >> 3;                 // 0..63
        int mw = (lin & 7) * 8;            // 0..56
        short8 v;
#pragma unroll
        for (int j = 0; j < 8; ++j) v[j] = (short)tile[mw + j][dw];
        int kt = (m0 + mw) >> 5;
        int mm = mw & 31;
        *(short8*)(v3 + ((size_t)(bh * 32 + kt) * 64 + dw) * 32 + mm) = v;
    }
}

// ---------- fused attention: depth-3 LDS K pipeline + head-group XCD swizzle ----------
// 1-D grid 3072. Blocks sharing a mask tile (b, n0, h=0..11) map to one XCD.
// V pipeline = R5-proven (issue at PV start; short live ranges, no barriers crossed).
__global__ __launch_bounds__(256, 3) void attn_kernel(
    const unsigned short* __restrict__ qkvb, const unsigned short* __restrict__ kp,
    const unsigned short* __restrict__ v3, const float* __restrict__ mask,
    const float* __restrict__ weight, float* __restrict__ attn_out,
    unsigned short* __restrict__ outb)
{
    __shared__ char smem[49152];           // kstage 4 waves x 3 bufs x 4KB | later P[16][1032]
    __shared__ float red_max[4][16];
    __shared__ float red_sum[4][16];

    const int t = threadIdx.x;
    const int lane = t & 63;
    const int wv = t >> 6;
    const int li = lane & 15;
    const int g = lane >> 4;
    const int koff = g * 8;

    // head-group swizzle: 12 blocks with same (b, n0) and h=0..11 share bid&7 (one XCD)
    const int bid = blockIdx.x;
    const int xcd = bid & 7, slot = bid >> 3;
    const int h = slot % 12, gh = slot / 12;
    const int g12 = gh * 8 + xcd;          // in [0,256)
    const int b = g12 >> 6, nt = g12 & 63;
    const int n0 = nt * 16;
    const int bh = b * NH + h;
    const int cb = wv * 256;

    unsigned short* kw = (unsigned short*)smem + wv * 6144;   // 3 x 2048 shorts
    const unsigned short* kps = kp + (size_t)bh * 65536 + cb * 64;
    const float* mrow = mask + (size_t)b * NN * NN + (size_t)(n0 + li) * NN + cb + g * 4;

    // ---- prologue: weight (1 f32x4/lane), q frags
    f32x4 w4;
    gloadf4(w4, weight + b * NN + cb + lane * 4);
    const unsigned short* qp = qkvb + (size_t)(b * NN + n0 + li) * TC + h * 64 + koff;
    short8 qf0, qf1;
    gload16(qf0, qp);
    gload16(qf1, qp + 32);

    f32x4 acc[16];
    f32x4 mk[3][2];

    // stage chunk c (32 keys, 4KB) + its 2 mask f32x4s: 6 VMEM ops
#define KISSUE(c) do {                                                        \
        const unsigned short* ks_ = kps + (c) * 2048;                         \
        unsigned short* kd_ = kw + ((c) % 3) * 2048;                          \
        gload_lds16(ks_ + 0 * 512 + lane * 8, kd_ + 0 * 512 + lane * 8);      \
        gload_lds16(ks_ + 1 * 512 + lane * 8, kd_ + 1 * 512 + lane * 8);      \
        gload_lds16(ks_ + 2 * 512 + lane * 8, kd_ + 2 * 512 + lane * 8);      \
        gload_lds16(ks_ + 3 * 512 + lane * 8, kd_ + 3 * 512 + lane * 8);      \
        gloadf4(mk[(c) % 3][0], mrow + ((c) * 2 + 0) * 16);                   \
        gloadf4(mk[(c) % 3][1], mrow + ((c) * 2 + 1) * 16);                   \
    } while (0)

    // compute chunk c: 2 cf (16 keys each), swizzled ds_read_b128 frags, mask as C-in
#define KSTEP(c) do {                                                         \
        const unsigned short* kb_ = kw + ((c) % 3) * 2048;                    \
        const int swz_ = (li & 7) << 4;                                       \
        _Pragma("unroll")                                                     \
        for (int s = 0; s < 2; ++s) {                                         \
            const int keyb_ = (s * 16 + li) * 64;                             \
            short8 kf0 = *(const short8*)&kb_[keyb_ + (((g * 16) ^ swz_) >> 1)];        \
            short8 kf1 = *(const short8*)&kb_[keyb_ + (((64 + g * 16) ^ swz_) >> 1)];   \
            f32x4 ci = mk[(c) % 3][s] * 96.0f;                                \
            ci = __builtin_amdgcn_mfma_f32_16x16x32_bf16(kf0, qf0, ci, 0, 0, 0); \
            ci = __builtin_amdgcn_mfma_f32_16x16x32_bf16(kf1, qf1, ci, 0, 0, 0); \
            acc[(c) * 2 + s] = ci;                                            \
        }                                                                     \
    } while (0)

    KISSUE(0); KISSUE(1); KISSUE(2);
    WAITV(12); KSTEP(0); SBAR(); KISSUE(3);
    WAITV(12); KSTEP(1); SBAR(); KISSUE(4);
    WAITV(12); KSTEP(2); SBAR(); KISSUE(5);
    WAITV(12); KSTEP(3); SBAR(); KISSUE(6);
    WAITV(12); KSTEP(4); SBAR(); KISSUE(7);
    WAITV(12); KSTEP(5); SBAR();
    WAITV(6);  KSTEP(6); SBAR();
    WAITV(0);  KSTEP(7);
#undef KISSUE
#undef KSTEP

    // ---- row max (acc = s*96; monotone)
    const float scale = 1.0f / 96.0f;
    float rmax = -1e30f;
#pragma unroll
    for (int cf = 0; cf < 16; ++cf) {
#pragma unroll
        for (int r = 0; r < 4; ++r) rmax = fmaxf(rmax, acc[cf][r]);
    }
    rmax = fmaxf(rmax, __shfl_xor(rmax, 16, 64));
    rmax = fmaxf(rmax, __shfl_xor(rmax, 32, 64));
    if (lane < 16) red_max[wv][lane] = rmax;
    __syncthreads();                       // all waves done with kstage LDS
    rmax = fmaxf(fmaxf(red_max[0][li], red_max[1][li]),
                 fmaxf(red_max[2][li], red_max[3][li])) * scale;

    // ---- p = exp(s-max)*w; stage bf16 p into LDS (overlays kstage); weighted row sum
    unsigned short (*P)[1032] = (unsigned short(*)[1032])smem;
    float rsum = 0.f;
#pragma unroll
    for (int cf = 0; cf < 16; ++cf) {
        f32x4 wcf;
#pragma unroll
        for (int r = 0; r < 4; ++r) wcf[r] = __shfl(w4[r], cf * 4 + g, 64);
        u16x4 pb;
#pragma unroll
        for (int r = 0; r < 4; ++r) {
            float p = __expf(acc[cf][r] * scale - rmax) * (wcf[r] + 1e-10f);
            acc[cf][r] = p;
            rsum += p;
            pb[r] = f2bf(p);
        }
        *(u16x4*)&P[li][cb + cf * 16 + g * 4] = pb;
    }
    rsum += __shfl_xor(rsum, 16, 64);
    rsum += __shfl_xor(rsum, 32, 64);
    if (lane < 16) red_sum[wv][lane] = rsum;
    __syncthreads();                       // covers P writes + red_sum

    // ---- PV: frag-packed V, depth-2 register pipeline (R5-proven placement)
    f32x4 o = {};
    const unsigned short* v3s = v3 + (size_t)bh * 65536 + wv * 512 + li * 32 + g * 8;
    short8 vA[8], vB[8];
#define VISSUE(c, vb2) do {                                                   \
        _Pragma("unroll")                                                     \
        for (int j2 = 0; j2 < 8; ++j2) gload16(vb2[j2], v3s + ((c) * 8 + j2) * 2048); \
    } while (0)
#define VCOMP(c, vb2) do {                                                    \
        _Pragma("unroll")                                                     \
        for (int j2 = 0; j2 < 8; ++j2) {                                      \
            short8 pa = *(const short8*)&P[li][((c) * 8 + j2) * 32 + koff];   \
            o = __builtin_amdgcn_mfma_f32_16x16x32_bf16(pa, vb2[j2], o, 0, 0, 0); \
        }                                                                     \
    } while (0)
    VISSUE(0, vA);
    VISSUE(1, vB);
    WAITV(8);  VCOMP(0, vA); SBAR(); VISSUE(2, vA);
    WAITV(8);  VCOMP(1, vB); SBAR(); VISSUE(3, vB);
    WAITV(8);  VCOMP(2, vA);
    WAITV(0);  VCOMP(3, vB);
#undef VISSUE
#undef VCOMP

    // ---- epilogue: outb (bf16, normalized) then attn f32 stores (fire-and-forget)
    const float rinv = 1.0f / (red_sum[0][li] + red_sum[1][li]
                             + red_sum[2][li] + red_sum[3][li]);
    const int dcol = h * 64 + wv * 16 + li;
#pragma unroll
    for (int r = 0; r < 4; ++r) {
        const int row = g * 4 + r;
        const float rv = 1.0f / (red_sum[0][row] + red_sum[1][row]
                               + red_sum[2][row] + red_sum[3][row]);
        outb[(size_t)(b * NN + n0 + row) * NC + dcol] = f2bf(o[r] * rv);
    }

    float* arow = attn_out + (size_t)bh * NN * NN + (size_t)(n0 + li) * NN + cb + g * 4;
#pragma unroll
    for (int cf = 0; cf < 16; ++cf) {
        f32x4 a4;
#pragma unroll
        for (int r = 0; r < 4; ++r) a4[r] = acc[cf][r] * rinv;
        *(f32x4*)(arow + cf * 16) = a4;
    }
}

// ---------- launch ----------
extern "C" void kernel_launch(void* const* d_in, const int* in_sizes, int n_in,
                              void* d_out, int out_size, void* d_ws, size_t ws_size,
                              hipStream_t stream) {
    const float* x      = (const float*)d_in[0];
    const float* mask   = (const float*)d_in[1];
    const float* weight = (const float*)d_in[2];
    const float* qkv_w  = (const float*)d_in[3];
    const float* mu_w   = (const float*)d_in[4];
    const float* mu_b   = (const float*)d_in[5];
    const float* ls_w   = (const float*)d_in[6];
    const float* ls_b   = (const float*)d_in[7];

    char* ws = (char*)d_ws;
    unsigned short* xb   = (unsigned short*)(ws + OFF_XB);   // becomes kp after gemm_qkv
    unsigned short* kp   = (unsigned short*)(ws + OFF_XB);
    unsigned short* wq   = (unsigned short*)(ws + OFF_WQ);
    unsigned short* wmu  = (unsigned short*)(ws + OFF_WMU);
    unsigned short* wls  = (unsigned short*)(ws + OFF_WLS);
    unsigned short* qkvb = (unsigned short*)(ws + OFF_QKVB);
    unsigned short* v3   = (unsigned short*)(ws + OFF_V3);
    unsigned short* outb = (unsigned short*)(ws + OFF_OUTB);

    float* out_mu   = (float*)d_out;                 // (4,1024,768)
    float* out_ls   = out_mu + 3145728;              // (4,1024,768)
    float* out_attn = out_mu + 6291456;              // (4,12,1024,1024)

    cast_all<<<5376, 256, 0, stream>>>(x, qkv_w, mu_w, ls_w, xb);

    gemm_qkv<<<dim3(TC / 128, 4096 / 128), 256, 0, stream>>>(xb, wq, qkvb);

    pack_kv<<<dim3(NN / 64, NB * NH), 256, 0, stream>>>(qkvb, kp, v3);

    attn_kernel<<<3072, 256, 0, stream>>>(
        qkvb, kp, v3, mask, weight, out_attn, outb);

    gemm_heads<<<dim3(NC / 128, 4096 / 128, 2), 256, 0, stream>>>(
        outb, wmu, wls, mu_b, ls_b, out_mu, out_ls);
}

// Round 9
// 151.416 us; speedup vs baseline: 1.2095x; 1.2095x over previous
//
#include <hip/hip_runtime.h>
#include <hip/hip_bf16.h>

// ---------- types ----------
typedef __attribute__((ext_vector_type(8))) short short8;      // 8 x bf16 (4 VGPR) MFMA frag
typedef __attribute__((ext_vector_type(4))) float f32x4;       // MFMA accumulator
typedef __attribute__((ext_vector_type(4))) unsigned short u16x4;

// ---------- constants ----------
#define NB 4
#define NN 1024
#define NC 768
#define NH 12
#define TC 2304

// workspace byte offsets (kp reuses xb region: xb dead after gemm_qkv)
#define OFF_XB   0ul
#define OFF_WQ   6291456ul
#define OFF_WMU  (OFF_WQ + 3538944ul)
#define OFF_WLS  (OFF_WMU + 589824ul)
#define OFF_QKVB (OFF_WLS + 589824ul)
#define OFF_V3   (OFF_QKVB + 18874368ul)
#define OFF_OUTB (OFF_V3 + 6291456ul)

__device__ __forceinline__ unsigned short f2bf(float f) {
    unsigned int u = __float_as_uint(f);
    u = (u + 0x7FFFu + ((u >> 16) & 1u)) >> 16;
    return (unsigned short)u;
}

__device__ __forceinline__ void gload_lds16(const unsigned short* g, unsigned short* l) {
    __builtin_amdgcn_global_load_lds(
        (const __attribute__((address_space(1))) unsigned int*)g,
        (__attribute__((address_space(3))) unsigned int*)l, 16, 0, 0);
}

__device__ __forceinline__ void gload16(short8& dst, const unsigned short* p) {
    asm volatile("global_load_dwordx4 %0, %1, off" : "=v"(dst) : "v"(p));
}
__device__ __forceinline__ void gloadf4(f32x4& dst, const float* p) {
    asm volatile("global_load_dwordx4 %0, %1, off" : "=v"(dst) : "v"(p));
}
#define WAITV(N) do { asm volatile("s_waitcnt vmcnt(" #N ")" ::: "memory"); \
                      __builtin_amdgcn_sched_barrier(0); } while (0)
#define SBAR()   __builtin_amdgcn_sched_barrier(0)

// ---------- fused cast f32 -> bf16 ----------
__global__ void cast_all(const float* __restrict__ x, const float* __restrict__ qkv_w,
                         const float* __restrict__ mu_w, const float* __restrict__ ls_w,
                         unsigned short* __restrict__ dst) {
    int i = blockIdx.x * blockDim.x + threadIdx.x;
    const float* src; int off;
    if (i < 786432)            { src = x;     off = i; }
    else if (i < 1228800)      { src = qkv_w; off = i - 786432; }
    else if (i < 1302528)      { src = mu_w;  off = i - 1228800; }
    else                       { src = ls_w;  off = i - 1302528; }
    f32x4 v = ((const f32x4*)src)[off];
    u16x4 o;
#pragma unroll
    for (int j = 0; j < 4; ++j) o[j] = f2bf(v[j]);
    ((u16x4*)dst)[i] = o;
}

// ---------- shared GEMM body (validated) ----------
template <int EPI>
__device__ __forceinline__ void gemm_body(
    unsigned short* As, unsigned short* Bs,
    const unsigned short* __restrict__ A, const unsigned short* __restrict__ Bm,
    int K, int lda, int ldb, void* __restrict__ Cout, int ldc,
    const float* __restrict__ bias, int row0, int col0)
{
    const int t = threadIdx.x;
    const int lane = t & 63;
    const int wv = t >> 6;
    const int wm = wv >> 1, wn = wv & 1;
    const int li = lane & 15;
    const int koff = (lane >> 4) * 8;

    f32x4 acc[4][4] = {};

    const int tr = t >> 2;
    const int tc = (t & 3) * 8;
    const unsigned short* ag = A + (size_t)(row0 + tr) * lda + tc;
    const unsigned short* bg = Bm + (size_t)(col0 + tr) * ldb + tc;

    for (int kt = 0; kt < K; kt += 32) {
        gload_lds16(ag,            As + t * 8);
        gload_lds16(ag + 64 * lda, As + 2048 + t * 8);
        gload_lds16(bg,            Bs + t * 8);
        gload_lds16(bg + 64 * ldb, Bs + 2048 + t * 8);
        ag += 32; bg += 32;
        __syncthreads();
        short8 af[4], bf[4];
#pragma unroll
        for (int m = 0; m < 4; ++m)
            af[m] = *(const short8*)&As[(wm * 64 + m * 16 + li) * 32 + koff];
#pragma unroll
        for (int n = 0; n < 4; ++n)
            bf[n] = *(const short8*)&Bs[(wn * 64 + n * 16 + li) * 32 + koff];
#pragma unroll
        for (int m = 0; m < 4; ++m)
#pragma unroll
            for (int n = 0; n < 4; ++n)
                acc[m][n] = __builtin_amdgcn_mfma_f32_16x16x32_bf16(af[m], bf[n], acc[m][n], 0, 0, 0);
        __syncthreads();
    }

#pragma unroll
    for (int m = 0; m < 4; ++m) {
        const int row = row0 + wm * 64 + m * 16 + (lane >> 4) * 4;
#pragma unroll
        for (int n = 0; n < 4; ++n) {
            const int col = col0 + wn * 64 + n * 16 + li;
#pragma unroll
            for (int r = 0; r < 4; ++r) {
                if (EPI == 0) {
                    ((unsigned short*)Cout)[(size_t)(row + r) * ldc + col] = f2bf(acc[m][n][r]);
                } else {
                    ((float*)Cout)[(size_t)(row + r) * ldc + col] = acc[m][n][r] + bias[col];
                }
            }
        }
    }
}

__global__ __launch_bounds__(256, 2) void gemm_qkv(
    const unsigned short* __restrict__ A, const unsigned short* __restrict__ Bm,
    unsigned short* __restrict__ C)
{
    __shared__ unsigned short As[128 * 32];
    __shared__ unsigned short Bs[128 * 32];
    const int bid = blockIdx.y * gridDim.x + blockIdx.x;
    const int nwg = gridDim.x * gridDim.y;
    const int swz = (bid & 7) * (nwg >> 3) + (bid >> 3);
    const int row0 = (swz / gridDim.x) * 128;
    const int col0 = (swz % gridDim.x) * 128;
    gemm_body<0>(As, Bs, A, Bm, NC, NC, NC, C, TC, nullptr, row0, col0);
}

__global__ __launch_bounds__(256, 2) void gemm_heads(
    const unsigned short* __restrict__ outb,
    const unsigned short* __restrict__ wmu, const unsigned short* __restrict__ wls,
    const float* __restrict__ mu_b, const float* __restrict__ ls_b,
    float* __restrict__ out_mu, float* __restrict__ out_ls)
{
    __shared__ unsigned short As[128 * 32];
    __shared__ unsigned short Bs[128 * 32];
    const int bid = blockIdx.y * gridDim.x + blockIdx.x;
    const int nwg = gridDim.x * gridDim.y;
    const int swz = (bid & 7) * (nwg >> 3) + (bid >> 3);
    const int row0 = (swz / gridDim.x) * 128;
    const int col0 = (swz % gridDim.x) * 128;
    const int z = blockIdx.z;
    gemm_body<1>(As, Bs, outb + (z ? 384 : 0), z ? wls : wmu, 384, NC, 384,
                 z ? (void*)out_ls : (void*)out_mu, NC, z ? ls_b : mu_b, row0, col0);
}

// ---------- pack K (swizzled per-head rows) + V (frag-order) ----------
__global__ __launch_bounds__(256, 4) void pack_kv(
    const unsigned short* __restrict__ qkvb, unsigned short* __restrict__ kp,
    unsigned short* __restrict__ v3)
{
    __shared__ unsigned short tile[64][65];
    const int t = threadIdx.x;
    const int bh = blockIdx.y;
    const int b = bh / NH, h = bh % NH;
    const int m0 = blockIdx.x * 64;
#pragma unroll
    for (int i = 0; i < 2; ++i) {
        int lin = i * 256 + t;
        int mr = lin >> 3;
        int dr = (lin & 7) * 8;
        short8 v = *(const short8*)(qkvb + (size_t)(b * NN + m0 + mr) * TC + 768 + h * 64 + dr);
        int dbyte = (dr * 2) ^ ((mr & 7) << 4);
        *(short8*)(kp + (size_t)(bh * NN + m0 + mr) * 64 + (dbyte >> 1)) = v;
    }
#pragma unroll
    for (int i = 0; i < 2; ++i) {
        int lin = i * 256 + t;
        int mr = lin >> 3;
        int dr = (lin & 7) * 8;
        short8 v = *(const short8*)(qkvb + (size_t)(b * NN + m0 + mr) * TC + 1536 + h * 64 + dr);
#pragma unroll
        for (int j = 0; j < 8; ++j) tile[mr][dr + j] = (unsigned short)v[j];
    }
    __syncthreads();
#pragma unroll
    for (int i = 0; i < 2; ++i) {
        int lin = i * 256 + t;
        int dw = lin >> 3;
        int mw = (lin & 7) * 8;
        short8 v;
#pragma unroll
        for (int j = 0; j < 8; ++j) v[j] = (short)tile[mw + j][dw];
        int kt = (m0 + mw) >> 5;
        int mm = mw & 31;
        *(short8*)(v3 + ((size_t)(bh * 32 + kt) * 64 + dw) * 32 + mm) = v;
    }
}

// ---------- fused attention: 8 waves/block, 128 keys/wave, split-k PV, nt stores ----------
// grid (64, 48); block 512 = 8 waves. Wave wv owns key cols [wv*128, wv*128+128).
// PV: waves 0-3 k<512, waves 4-7 k>=512 on d-block (wv&3); partial O merged via LDS.
__global__ __launch_bounds__(512, 4) void attn_kernel(
    const unsigned short* __restrict__ qkvb, const unsigned short* __restrict__ kp,
    const unsigned short* __restrict__ v3, const float* __restrict__ mask,
    const float* __restrict__ weight, float* __restrict__ attn_out,
    unsigned short* __restrict__ outb)
{
    __shared__ char smem[65536];           // kstage 8 waves x 2 bufs x 4KB | later P[16][1032]
    __shared__ float red_max[8][16];
    __shared__ float red_sum[8][16];
    __shared__ f32x4 po[4][64];            // PV partial-O exchange (waves 4-7 -> 0-3)

    const int t = threadIdx.x;
    const int lane = t & 63;
    const int wv = t >> 6;                 // 0..7
    const int li = lane & 15;
    const int g = lane >> 4;
    const int koff = g * 8;
    const int bh = blockIdx.y;
    const int b = bh / NH, h = bh % NH;
    const int n0 = blockIdx.x * 16;
    const int cb = wv * 128;

    unsigned short* kw = (unsigned short*)smem + wv * 4096;   // 2 bufs x 2048 shorts
    const unsigned short* kps = kp + (size_t)bh * 65536 + cb * 64;
    const float* mrow = mask + (size_t)b * NN * NN + (size_t)(n0 + li) * NN + cb + g * 4;

    // weight stripe (128 cols): lanes 0-31 cover it; 32-63 duplicate (stay in-bounds)
    f32x4 w4;
    gloadf4(w4, weight + b * NN + cb + (lane & 31) * 4);
    const unsigned short* qp = qkvb + (size_t)(b * NN + n0 + li) * TC + h * 64 + koff;
    short8 qf0, qf1;
    gload16(qf0, qp);
    gload16(qf1, qp + 32);

    f32x4 acc[8];
    f32x4 mk[2][2];

    // stage chunk c (32 keys, 4KB) + its 2 mask f32x4s: 6 VMEM ops
#define KISSUE(c) do {                                                        \
        const unsigned short* ks_ = kps + (c) * 2048;                         \
        unsigned short* kd_ = kw + ((c) & 1) * 2048;                          \
        gload_lds16(ks_ + 0 * 512 + lane * 8, kd_ + 0 * 512 + lane * 8);      \
        gload_lds16(ks_ + 1 * 512 + lane * 8, kd_ + 1 * 512 + lane * 8);      \
        gload_lds16(ks_ + 2 * 512 + lane * 8, kd_ + 2 * 512 + lane * 8);      \
        gload_lds16(ks_ + 3 * 512 + lane * 8, kd_ + 3 * 512 + lane * 8);      \
        gloadf4(mk[(c) & 1][0], mrow + ((c) * 2 + 0) * 16);                   \
        gloadf4(mk[(c) & 1][1], mrow + ((c) * 2 + 1) * 16);                   \
    } while (0)

#define KSTEP(c) do {                                                         \
        const unsigned short* kb_ = kw + ((c) & 1) * 2048;                    \
        const int swz_ = (li & 7) << 4;                                       \
        _Pragma("unroll")                                                     \
        for (int s = 0; s < 2; ++s) {                                         \
            const int keyb_ = (s * 16 + li) * 64;                             \
            short8 kf0 = *(const short8*)&kb_[keyb_ + (((g * 16) ^ swz_) >> 1)];        \
            short8 kf1 = *(const short8*)&kb_[keyb_ + (((64 + g * 16) ^ swz_) >> 1)];   \
            f32x4 ci = mk[(c) & 1][s] * 96.0f;                                \
            ci = __builtin_amdgcn_mfma_f32_16x16x32_bf16(kf0, qf0, ci, 0, 0, 0); \
            ci = __builtin_amdgcn_mfma_f32_16x16x32_bf16(kf1, qf1, ci, 0, 0, 0); \
            acc[(c) * 2 + s] = ci;                                            \
        }                                                                     \
    } while (0)

    KISSUE(0); KISSUE(1);
    WAITV(6);  KSTEP(0); SBAR(); KISSUE(2);
    WAITV(6);  KSTEP(1); SBAR(); KISSUE(3);
    WAITV(6);  KSTEP(2); SBAR();
    WAITV(0);  KSTEP(3);
#undef KISSUE
#undef KSTEP

    // ---- row max (acc = s*96; monotone)
    const float scale = 1.0f / 96.0f;
    float rmax = -1e30f;
#pragma unroll
    for (int cf = 0; cf < 8; ++cf) {
#pragma unroll
        for (int r = 0; r < 4; ++r) rmax = fmaxf(rmax, acc[cf][r]);
    }
    rmax = fmaxf(rmax, __shfl_xor(rmax, 16, 64));
    rmax = fmaxf(rmax, __shfl_xor(rmax, 32, 64));
    if (lane < 16) red_max[wv][lane] = rmax;
    __syncthreads();                       // all waves done with kstage LDS
    {
        float m01 = fmaxf(red_max[0][li], red_max[1][li]);
        float m23 = fmaxf(red_max[2][li], red_max[3][li]);
        float m45 = fmaxf(red_max[4][li], red_max[5][li]);
        float m67 = fmaxf(red_max[6][li], red_max[7][li]);
        rmax = fmaxf(fmaxf(m01, m23), fmaxf(m45, m67)) * scale;
    }

    // ---- p = exp(s-max)*w; stage bf16 p into LDS (overlays kstage); weighted row sum
    unsigned short (*P)[1032] = (unsigned short(*)[1032])smem;
    float rsum = 0.f;
#pragma unroll
    for (int cf = 0; cf < 8; ++cf) {
        f32x4 wcf;
#pragma unroll
        for (int r = 0; r < 4; ++r) wcf[r] = __shfl(w4[r], cf * 4 + g, 64);
        u16x4 pb;
#pragma unroll
        for (int r = 0; r < 4; ++r) {
            float p = __expf(acc[cf][r] * scale - rmax) * (wcf[r] + 1e-10f);
            acc[cf][r] = p;
            rsum += p;
            pb[r] = f2bf(p);
        }
        *(u16x4*)&P[li][cb + cf * 16 + g * 4] = pb;
    }
    rsum += __shfl_xor(rsum, 16, 64);
    rsum += __shfl_xor(rsum, 32, 64);
    if (lane < 16) red_sum[wv][lane] = rsum;
    __syncthreads();                       // covers P writes + red_sum

    // ---- PV: split-k. d-block p4 = wv&3 (16 cols), k-half hf = wv>>2 (512 keys = 16 kts)
    const int p4 = wv & 3, hf = wv >> 2;
    f32x4 o = {};
    const unsigned short* v3s = v3 + (size_t)bh * 65536 + (size_t)(hf * 16) * 2048
                                  + p4 * 512 + li * 32 + g * 8;
    short8 vA[4], vB[4];
#define VISSUE(c, vb2) do {                                                   \
        _Pragma("unroll")                                                     \
        for (int j2 = 0; j2 < 4; ++j2) gload16(vb2[j2], v3s + ((c) * 4 + j2) * 2048); \
    } while (0)
#define VCOMP(c, vb2) do {                                                    \
        _Pragma("unroll")                                                     \
        for (int j2 = 0; j2 < 4; ++j2) {                                      \
            short8 pa = *(const short8*)&P[li][(hf * 16 + (c) * 4 + j2) * 32 + koff]; \
            o = __builtin_amdgcn_mfma_f32_16x16x32_bf16(pa, vb2[j2], o, 0, 0, 0); \
        }                                                                     \
    } while (0)
    VISSUE(0, vA);
    VISSUE(1, vB);
    WAITV(4);  VCOMP(0, vA); SBAR(); VISSUE(2, vA);
    WAITV(4);  VCOMP(1, vB); SBAR(); VISSUE(3, vB);
    WAITV(4);  VCOMP(2, vA);
    WAITV(0);  VCOMP(3, vB);
#undef VISSUE
#undef VCOMP

    // ---- merge k-halves: waves 4-7 publish, waves 0-3 add + store outb
    if (wv >= 4) po[p4][lane] = o;
    __syncthreads();
    if (wv < 4) {
        f32x4 oo = po[p4][lane];
        const int dcol = h * 64 + p4 * 16 + li;
#pragma unroll
        for (int r = 0; r < 4; ++r) {
            const int row = g * 4 + r;
            const float rs = red_sum[0][row] + red_sum[1][row] + red_sum[2][row]
                           + red_sum[3][row] + red_sum[4][row] + red_sum[5][row]
                           + red_sum[6][row] + red_sum[7][row];
            outb[(size_t)(b * NN + n0 + row) * NC + dcol] = f2bf((o[r] + oo[r]) / rs);
        }
    }

    // ---- attn f32 stores: non-temporal (don't pollute L2/L3), fire-and-forget
    const float rinv = 1.0f / (red_sum[0][li] + red_sum[1][li] + red_sum[2][li]
                             + red_sum[3][li] + red_sum[4][li] + red_sum[5][li]
                             + red_sum[6][li] + red_sum[7][li]);
    float* arow = attn_out + (size_t)bh * NN * NN + (size_t)(n0 + li) * NN + cb + g * 4;
#pragma unroll
    for (int cf = 0; cf < 8; ++cf) {
        f32x4 a4;
#pragma unroll
        for (int r = 0; r < 4; ++r) a4[r] = acc[cf][r] * rinv;
        __builtin_nontemporal_store(a4, (f32x4*)(arow + cf * 16));
    }
}

// ---------- launch ----------
extern "C" void kernel_launch(void* const* d_in, const int* in_sizes, int n_in,
                              void* d_out, int out_size, void* d_ws, size_t ws_size,
                              hipStream_t stream) {
    const float* x      = (const float*)d_in[0];
    const float* mask   = (const float*)d_in[1];
    const float* weight = (const float*)d_in[2];
    const float* qkv_w  = (const float*)d_in[3];
    const float* mu_w   = (const float*)d_in[4];
    const float* mu_b   = (const float*)d_in[5];
    const float* ls_w   = (const float*)d_in[6];
    const float* ls_b   = (const float*)d_in[7];

    char* ws = (char*)d_ws;
    unsigned short* xb   = (unsigned short*)(ws + OFF_XB);
    unsigned short* kp   = (unsigned short*)(ws + OFF_XB);
    unsigned short* wq   = (unsigned short*)(ws + OFF_WQ);
    unsigned short* wmu  = (unsigned short*)(ws + OFF_WMU);
    unsigned short* wls  = (unsigned short*)(ws + OFF_WLS);
    unsigned short* qkvb = (unsigned short*)(ws + OFF_QKVB);
    unsigned short* v3   = (unsigned short*)(ws + OFF_V3);
    unsigned short* outb = (unsigned short*)(ws + OFF_OUTB);

    float* out_mu   = (float*)d_out;
    float* out_ls   = out_mu + 3145728;
    float* out_attn = out_mu + 6291456;

    cast_all<<<5376, 256, 0, stream>>>(x, qkv_w, mu_w, ls_w, xb);

    gemm_qkv<<<dim3(TC / 128, 4096 / 128), 256, 0, stream>>>(xb, wq, qkvb);

    pack_kv<<<dim3(NN / 64, NB * NH), 256, 0, stream>>>(qkvb, kp, v3);

    attn_kernel<<<dim3(NN / 16, NB * NH), 512, 0, stream>>>(
        qkvb, kp, v3, mask, weight, out_attn, outb);

    gemm_heads<<<dim3(NC / 128, 4096 / 128, 2), 256, 0, stream>>>(
        outb, wmu, wls, mu_b, ls_b, out_mu, out_ls);
}

// Round 10
// 151.326 us; speedup vs baseline: 1.2103x; 1.0006x over previous
//
#include <hip/hip_runtime.h>
#include <hip/hip_bf16.h>

// ---------- types ----------
typedef __attribute__((ext_vector_type(8))) short short8;      // 8 x bf16 (4 VGPR) MFMA frag
typedef __attribute__((ext_vector_type(4))) float f32x4;       // MFMA accumulator
typedef __attribute__((ext_vector_type(4))) unsigned short u16x4;

// ---------- constants ----------
#define NB 4
#define NN 1024
#define NC 768
#define NH 12
#define TC 2304

// workspace byte offsets
#define OFF_XB   0ul
#define OFF_WQ   6291456ul
#define OFF_WMU  (OFF_WQ + 3538944ul)
#define OFF_WLS  (OFF_WMU + 589824ul)
#define OFF_QKVB (OFF_WLS + 589824ul)
#define OFF_V3   (OFF_QKVB + 18874368ul)
#define OFF_OUTB (OFF_V3 + 6291456ul)

__device__ __forceinline__ unsigned short f2bf(float f) {
    unsigned int u = __float_as_uint(f);
    u = (u + 0x7FFFu + ((u >> 16) & 1u)) >> 16;
    return (unsigned short)u;
}

__device__ __forceinline__ void gload_lds16(const unsigned short* g, unsigned short* l) {
    __builtin_amdgcn_global_load_lds(
        (const __attribute__((address_space(1))) unsigned int*)g,
        (__attribute__((address_space(3))) unsigned int*)l, 16, 0, 0);
}

__device__ __forceinline__ void gload16(short8& dst, const unsigned short* p) {
    asm volatile("global_load_dwordx4 %0, %1, off" : "=v"(dst) : "v"(p));
}
#define WAITV(N) do { asm volatile("s_waitcnt vmcnt(" #N ")" ::: "memory"); \
                      __builtin_amdgcn_sched_barrier(0); } while (0)
#define SBAR()   __builtin_amdgcn_sched_barrier(0)

// ---------- fused cast f32 -> bf16 ----------
__global__ void cast_all(const float* __restrict__ x, const float* __restrict__ qkv_w,
                         const float* __restrict__ mu_w, const float* __restrict__ ls_w,
                         unsigned short* __restrict__ dst) {
    int i = blockIdx.x * blockDim.x + threadIdx.x;
    const float* src; int off;
    if (i < 786432)            { src = x;     off = i; }
    else if (i < 1228800)      { src = qkv_w; off = i - 786432; }
    else if (i < 1302528)      { src = mu_w;  off = i - 1228800; }
    else                       { src = ls_w;  off = i - 1302528; }
    f32x4 v = ((const f32x4*)src)[off];
    u16x4 o;
#pragma unroll
    for (int j = 0; j < 4; ++j) o[j] = f2bf(v[j]);
    ((u16x4*)dst)[i] = o;
}

// ---------- shared GEMM body (validated) ----------
template <int EPI>
__device__ __forceinline__ void gemm_body(
    unsigned short* As, unsigned short* Bs,
    const unsigned short* __restrict__ A, const unsigned short* __restrict__ Bm,
    int K, int lda, int ldb, void* __restrict__ Cout, int ldc,
    const float* __restrict__ bias, int row0, int col0)
{
    const int t = threadIdx.x;
    const int lane = t & 63;
    const int wv = t >> 6;
    const int wm = wv >> 1, wn = wv & 1;
    const int li = lane & 15;
    const int koff = (lane >> 4) * 8;

    f32x4 acc[4][4] = {};

    const int tr = t >> 2;
    const int tc = (t & 3) * 8;
    const unsigned short* ag = A + (size_t)(row0 + tr) * lda + tc;
    const unsigned short* bg = Bm + (size_t)(col0 + tr) * ldb + tc;

    for (int kt = 0; kt < K; kt += 32) {
        gload_lds16(ag,            As + t * 8);
        gload_lds16(ag + 64 * lda, As + 2048 + t * 8);
        gload_lds16(bg,            Bs + t * 8);
        gload_lds16(bg + 64 * ldb, Bs + 2048 + t * 8);
        ag += 32; bg += 32;
        __syncthreads();
        short8 af[4], bf[4];
#pragma unroll
        for (int m = 0; m < 4; ++m)
            af[m] = *(const short8*)&As[(wm * 64 + m * 16 + li) * 32 + koff];
#pragma unroll
        for (int n = 0; n < 4; ++n)
            bf[n] = *(const short8*)&Bs[(wn * 64 + n * 16 + li) * 32 + koff];
#pragma unroll
        for (int m = 0; m < 4; ++m)
#pragma unroll
            for (int n = 0; n < 4; ++n)
                acc[m][n] = __builtin_amdgcn_mfma_f32_16x16x32_bf16(af[m], bf[n], acc[m][n], 0, 0, 0);
        __syncthreads();
    }

#pragma unroll
    for (int m = 0; m < 4; ++m) {
        const int row = row0 + wm * 64 + m * 16 + (lane >> 4) * 4;
#pragma unroll
        for (int n = 0; n < 4; ++n) {
            const int col = col0 + wn * 64 + n * 16 + li;
#pragma unroll
            for (int r = 0; r < 4; ++r) {
                if (EPI == 0) {
                    ((unsigned short*)Cout)[(size_t)(row + r) * ldc + col] = f2bf(acc[m][n][r]);
                } else {
                    ((float*)Cout)[(size_t)(row + r) * ldc + col] = acc[m][n][r] + bias[col];
                }
            }
        }
    }
}

__global__ __launch_bounds__(256, 2) void gemm_qkv(
    const unsigned short* __restrict__ A, const unsigned short* __restrict__ Bm,
    unsigned short* __restrict__ C)
{
    __shared__ unsigned short As[128 * 32];
    __shared__ unsigned short Bs[128 * 32];
    const int bid = blockIdx.y * gridDim.x + blockIdx.x;
    const int nwg = gridDim.x * gridDim.y;
    const int swz = (bid & 7) * (nwg >> 3) + (bid >> 3);
    const int row0 = (swz / gridDim.x) * 128;
    const int col0 = (swz % gridDim.x) * 128;
    gemm_body<0>(As, Bs, A, Bm, NC, NC, NC, C, TC, nullptr, row0, col0);
}

__global__ __launch_bounds__(256, 2) void gemm_heads(
    const unsigned short* __restrict__ outb,
    const unsigned short* __restrict__ wmu, const unsigned short* __restrict__ wls,
    const float* __restrict__ mu_b, const float* __restrict__ ls_b,
    float* __restrict__ out_mu, float* __restrict__ out_ls)
{
    __shared__ unsigned short As[128 * 32];
    __shared__ unsigned short Bs[128 * 32];
    const int bid = blockIdx.y * gridDim.x + blockIdx.x;
    const int nwg = gridDim.x * gridDim.y;
    const int swz = (bid & 7) * (nwg >> 3) + (bid >> 3);
    const int row0 = (swz / gridDim.x) * 128;
    const int col0 = (swz % gridDim.x) * 128;
    const int z = blockIdx.z;
    gemm_body<1>(As, Bs, outb + (z ? 384 : 0), z ? wls : wmu, 384, NC, 384,
                 z ? (void*)out_ls : (void*)out_mu, NC, z ? ls_b : mu_b, row0, col0);
}

// ---------- pack V only (frag-order): v3[bh][kt=m/32][d][m%32] ----------
__global__ __launch_bounds__(256, 4) void pack_v(
    const unsigned short* __restrict__ qkvb, unsigned short* __restrict__ v3)
{
    __shared__ unsigned short tile[64][65];
    const int t = threadIdx.x;
    const int bh = blockIdx.y;
    const int b = bh / NH, h = bh % NH;
    const int m0 = blockIdx.x * 64;
#pragma unroll
    for (int i = 0; i < 2; ++i) {
        int lin = i * 256 + t;
        int mr = lin >> 3;
        int dr = (lin & 7) * 8;
        short8 v = *(const short8*)(qkvb + (size_t)(b * NN + m0 + mr) * TC + 1536 + h * 64 + dr);
#pragma unroll
        for (int j = 0; j < 8; ++j) tile[mr][dr + j] = (unsigned short)v[j];
    }
    __syncthreads();
#pragma unroll
    for (int i = 0; i < 2; ++i) {
        int lin = i * 256 + t;
        int dw = lin >> 3;
        int mw = (lin & 7) * 8;
        short8 v;
#pragma unroll
        for (int j = 0; j < 8; ++j) v[j] = (short)tile[mw + j][dw];
        int kt = (m0 + mw) >> 5;
        int mm = mw & 31;
        *(short8*)(v3 + ((size_t)(bh * 32 + kt) * 64 + dw) * 32 + mm) = v;
    }
}

// ---------- fused attention: QBLK=32, cooperative K staging, split-k PV ----------
// grid (32, 48); block 512 = 8 waves. QK: wave (qs = wv>>2, ke = wv&3) covers
// q-subtile qs (16 rows) x key-eighth ke (32 keys) of each cooperative 128-key chunk.
// K staged straight from qkvb, XOR-swizzle folded into per-lane SOURCE address.
__global__ __launch_bounds__(512, 4) void attn_kernel(
    const unsigned short* __restrict__ qkvb, const unsigned short* __restrict__ v3,
    const float* __restrict__ mask, const float* __restrict__ weight,
    float* __restrict__ attn_out, unsigned short* __restrict__ outb)
{
    __shared__ __align__(16) char smem[66048];   // K dbuf 2x16KB | later P[32][1032]
    __shared__ f32x4 po[4][2][64];               // PV k-half exchange
    __shared__ float red_max[8][16];
    __shared__ float red_sum[8][16];

    const int t = threadIdx.x;
    const int lane = t & 63;
    const int wv = t >> 6;                 // 0..7
    const int li = lane & 15;
    const int g = lane >> 4;
    const int koff = g * 8;
    const int bh = blockIdx.y;
    const int b = bh / NH, h = bh % NH;
    const int n0 = blockIdx.x * 32;
    const int qs = wv >> 2;                // q-subtile 0..1
    const int ke = wv & 3;                 // key-eighth 0..3

    unsigned short* sm = (unsigned short*)smem;

    // q frags (B-operand): col = li -> q-row n0+qs*16+li
    const unsigned short* qp = qkvb + (size_t)(b * NN + n0 + qs * 16 + li) * TC + h * 64 + koff;
    short8 qf0 = *(const short8*)qp;
    short8 qf1 = *(const short8*)(qp + 32);

    // weight: lane l = ck*8 + s*4 + g holds cols ck*128 + ke*32 + s*16 + g*4 ..+4
    f32x4 w4 = *(const f32x4*)(weight + b * NN + (lane >> 3) * 128 + ke * 32
                               + ((lane >> 2) & 1) * 16 + (lane & 3) * 4);

    const float* mrow = mask + (size_t)b * NN * NN + (size_t)(n0 + qs * 16 + li) * NN
                      + ke * 32 + g * 4;

    const unsigned short* kgbase = qkvb + (size_t)(b * NN) * TC + 768 + h * 64;

    f32x4 acc[16];
    f32x4 mk[2][2];

    // cooperative stage of chunk ck (128 keys x 128B) into buf ck&1.
    // LDS dest per instr: uniform base + lane*16 (required). Source slot pre-XOR'd.
    auto stage = [&](int ck) {
#pragma unroll
        for (int i = 0; i < 2; ++i) {
            int m = wv * 16 + i * 8 + (lane >> 3);        // key within chunk
            int sl = (lane & 7) ^ (m & 7);                // swizzled 16B slot in source
            const unsigned short* src = kgbase + (size_t)(ck * 128 + m) * TC + sl * 8;
            unsigned short* dst = sm + (ck & 1) * 8192 + wv * 1024 + i * 512 + lane * 8;
            gload_lds16(src, dst);
        }
    };

    stage(0);
    mk[0][0] = *(const f32x4*)(mrow);
    mk[0][1] = *(const f32x4*)(mrow + 16);
    __syncthreads();                        // drains stage(0) + mk[0]

#pragma unroll
    for (int ck = 0; ck < 8; ++ck) {
        if (ck < 7) {
            stage(ck + 1);
            mk[(ck + 1) & 1][0] = *(const f32x4*)(mrow + (ck + 1) * 128);
            mk[(ck + 1) & 1][1] = *(const f32x4*)(mrow + (ck + 1) * 128 + 16);
        }
        const unsigned short* kbuf = sm + (ck & 1) * 8192;
#pragma unroll
        for (int s = 0; s < 2; ++s) {
            const int m = ke * 32 + s * 16 + li;          // key within chunk (frag row)
            short8 kf0 = *(const short8*)&kbuf[m * 64 + ((g ^ (m & 7)) * 8)];
            short8 kf1 = *(const short8*)&kbuf[m * 64 + (((g + 4) ^ (m & 7)) * 8)];
            f32x4 ci = mk[ck & 1][s] * 96.0f;             // mask as C-in (scale=1/96 exact)
            ci = __builtin_amdgcn_mfma_f32_16x16x32_bf16(kf0, qf0, ci, 0, 0, 0);
            ci = __builtin_amdgcn_mfma_f32_16x16x32_bf16(kf1, qf1, ci, 0, 0, 0);
            acc[ck * 2 + s] = ci;
        }
        __syncthreads();                    // drains next stage; guards buf reuse
    }

    // ---- row max (acc = s*96; monotone)
    const float scale = 1.0f / 96.0f;
    float rmax = -1e30f;
#pragma unroll
    for (int cf = 0; cf < 16; ++cf) {
#pragma unroll
        for (int r = 0; r < 4; ++r) rmax = fmaxf(rmax, acc[cf][r]);
    }
    rmax = fmaxf(rmax, __shfl_xor(rmax, 16, 64));
    rmax = fmaxf(rmax, __shfl_xor(rmax, 32, 64));
    if (lane < 16) red_max[wv][lane] = rmax;
    __syncthreads();
    rmax = fmaxf(fmaxf(red_max[qs * 4 + 0][li], red_max[qs * 4 + 1][li]),
                 fmaxf(red_max[qs * 4 + 2][li], red_max[qs * 4 + 3][li])) * scale;

    // ---- p = exp(s-max)*w; stage bf16 p into P (overlays K bufs); weighted row sum
    unsigned short (*P)[1032] = (unsigned short(*)[1032])smem;
    float rsum = 0.f;
#pragma unroll
    for (int cf = 0; cf < 16; ++cf) {
        f32x4 wcf;
#pragma unroll
        for (int r = 0; r < 4; ++r) wcf[r] = __shfl(w4[r], cf * 4 + g, 64);
        u16x4 pb;
#pragma unroll
        for (int r = 0; r < 4; ++r) {
            float p = __expf(acc[cf][r] * scale - rmax) * (wcf[r] + 1e-10f);
            acc[cf][r] = p;
            rsum += p;
            pb[r] = f2bf(p);
        }
        const int col = (cf >> 1) * 128 + ke * 32 + (cf & 1) * 16 + g * 4;
        *(u16x4*)&P[qs * 16 + li][col] = pb;
    }
    rsum += __shfl_xor(rsum, 16, 64);
    rsum += __shfl_xor(rsum, 32, 64);
    if (lane < 16) red_sum[wv][lane] = rsum;
    __syncthreads();                        // P complete + red_sum ready

    // ---- PV: wave (kh = wv>>2, p4 = wv&3): keys [kh*512,+512), d-cols [p4*16,+16),
    //      both q-subtiles share each V frag (8 MFMAs per 4-load chunk).
    const int kh = wv >> 2, p4 = wv & 3;
    f32x4 o0 = {}, o1 = {};
    const unsigned short* v3s = v3 + (size_t)bh * 65536 + (size_t)(kh * 16) * 2048
                              + p4 * 512 + li * 32 + g * 8;
    short8 vA[4], vB[4];
#define VISSUE(c, vb2) do {                                                   \
        _Pragma("unroll")                                                     \
        for (int j2 = 0; j2 < 4; ++j2) gload16(vb2[j2], v3s + ((c) * 4 + j2) * 2048); \
    } while (0)
#define VCOMP(c, vb2) do {                                                    \
        _Pragma("unroll")                                                     \
        for (int j2 = 0; j2 < 4; ++j2) {                                      \
            const int kt = kh * 16 + (c) * 4 + j2;                            \
            short8 pa0 = *(const short8*)&P[li][kt * 32 + koff];              \
            short8 pa1 = *(const short8*)&P[16 + li][kt * 32 + koff];         \
            o0 = __builtin_amdgcn_mfma_f32_16x16x32_bf16(pa0, vb2[j2], o0, 0, 0, 0); \
            o1 = __builtin_amdgcn_mfma_f32_16x16x32_bf16(pa1, vb2[j2], o1, 0, 0, 0); \
        }                                                                     \
    } while (0)
    VISSUE(0, vA);
    VISSUE(1, vB);
    WAITV(4);  VCOMP(0, vA); SBAR(); VISSUE(2, vA);
    WAITV(4);  VCOMP(1, vB); SBAR(); VISSUE(3, vB);
    WAITV(4);  VCOMP(2, vA);
    WAITV(0);  VCOMP(3, vB);
#undef VISSUE
#undef VCOMP

    // ---- merge k-halves
    if (kh == 1) { po[p4][0][lane] = o0; po[p4][1][lane] = o1; }
    __syncthreads();
    if (kh == 0) {
        f32x4 q0 = po[p4][0][lane];
        f32x4 q1 = po[p4][1][lane];
        const int dcol = h * 64 + p4 * 16 + li;
#pragma unroll
        for (int r = 0; r < 4; ++r) {
            const int rw = g * 4 + r;
            const float rs0 = red_sum[0][rw] + red_sum[1][rw] + red_sum[2][rw] + red_sum[3][rw];
            const float rs1 = red_sum[4][rw] + red_sum[5][rw] + red_sum[6][rw] + red_sum[7][rw];
            outb[(size_t)(b * NN + n0 + rw) * NC + dcol]      = f2bf((o0[r] + q0[r]) / rs0);
            outb[(size_t)(b * NN + n0 + 16 + rw) * NC + dcol] = f2bf((o1[r] + q1[r]) / rs1);
        }
    }

    // ---- attn f32 stores: non-temporal, full 64B lines per g-quad
    const float rinv = 1.0f / (red_sum[qs * 4 + 0][li] + red_sum[qs * 4 + 1][li]
                             + red_sum[qs * 4 + 2][li] + red_sum[qs * 4 + 3][li]);
    float* arow = attn_out + (size_t)bh * NN * NN + (size_t)(n0 + qs * 16 + li) * NN
                + ke * 32 + g * 4;
#pragma unroll
    for (int cf = 0; cf < 16; ++cf) {
        f32x4 a4;
#pragma unroll
        for (int r = 0; r < 4; ++r) a4[r] = acc[cf][r] * rinv;
        __builtin_nontemporal_store(a4, (f32x4*)(arow + (cf >> 1) * 128 + (cf & 1) * 16));
    }
}

// ---------- launch ----------
extern "C" void kernel_launch(void* const* d_in, const int* in_sizes, int n_in,
                              void* d_out, int out_size, void* d_ws, size_t ws_size,
                              hipStream_t stream) {
    const float* x      = (const float*)d_in[0];
    const float* mask   = (const float*)d_in[1];
    const float* weight = (const float*)d_in[2];
    const float* qkv_w  = (const float*)d_in[3];
    const float* mu_w   = (const float*)d_in[4];
    const float* mu_b   = (const float*)d_in[5];
    const float* ls_w   = (const float*)d_in[6];
    const float* ls_b   = (const float*)d_in[7];

    char* ws = (char*)d_ws;
    unsigned short* xb   = (unsigned short*)(ws + OFF_XB);
    unsigned short* wq   = (unsigned short*)(ws + OFF_WQ);
    unsigned short* wmu  = (unsigned short*)(ws + OFF_WMU);
    unsigned short* wls  = (unsigned short*)(ws + OFF_WLS);
    unsigned short* qkvb = (unsigned short*)(ws + OFF_QKVB);
    unsigned short* v3   = (unsigned short*)(ws + OFF_V3);
    unsigned short* outb = (unsigned short*)(ws + OFF_OUTB);

    float* out_mu   = (float*)d_out;
    float* out_ls   = out_mu + 3145728;
    float* out_attn = out_mu + 6291456;

    cast_all<<<5376, 256, 0, stream>>>(x, qkv_w, mu_w, ls_w, xb);

    gemm_qkv<<<dim3(TC / 128, 4096 / 128), 256, 0, stream>>>(xb, wq, qkvb);

    pack_v<<<dim3(NN / 64, NB * NH), 256, 0, stream>>>(qkvb, v3);

    attn_kernel<<<dim3(NN / 32, NB * NH), 512, 0, stream>>>(
        qkvb, v3, mask, weight, out_attn, outb);

    gemm_heads<<<dim3(NC / 128, 4096 / 128, 2), 256, 0, stream>>>(
        outb, wmu, wls, mu_b, ls_b, out_mu, out_ls);
}